// Round 4
// baseline (170.808 us; speedup 1.0000x reference)
//
#include <hip/hip_runtime.h>
#include <hip/hip_bf16.h>
#include <stdint.h>

// Problem constants
#define BS   8
#define CIN  256
#define COUT 256
#define SD   512
#define HH   64
#define WW   64
#define HP   66   // padded spatial dim

typedef __attribute__((ext_vector_type(8))) short short8;
typedef __attribute__((ext_vector_type(4))) float f32x4;

__device__ __forceinline__ unsigned short f2bf(float f) {
    __hip_bfloat16 h = __float2bfloat16(f);
    return *reinterpret_cast<unsigned short*>(&h);
}

typedef __attribute__((address_space(3))) unsigned int lds_u32_t;
typedef const __attribute__((address_space(1))) unsigned int glb_u32_t;

__device__ __forceinline__ void async16(const void* g, void* l) {
    __builtin_amdgcn_global_load_lds((glb_u32_t*)g, (lds_u32_t*)l, 16, 0, 0);
}

// ---------------------------------------------------------------------------
// K1: m[b,i] = s[b,:].aw[i,:] + ab[i] + 1
// grid 64 blocks: bx = b*8 + chunk(32 rows). 256 thr = 32 rows x 8 parts.
__global__ void k_style(const float* __restrict__ s, const float* __restrict__ aw,
                        const float* __restrict__ ab, float* __restrict__ m) {
    int b = blockIdx.x >> 3, chunk = blockIdx.x & 7;
    int tid = threadIdx.x;
    __shared__ float sv[SD];
    for (int d = tid; d < SD; d += 256) sv[d] = s[b * SD + d];
    __syncthreads();
    int il = tid >> 3, p = tid & 7;
    int i = chunk * 32 + il;
    const float4* awr = (const float4*)(aw + (size_t)i * SD + p * 64);
    float acc = 0.f;
#pragma unroll
    for (int d4 = 0; d4 < 16; ++d4) {
        float4 w4 = awr[d4];
        int d0 = p * 64 + d4 * 4;
        acc += w4.x * sv[d0] + w4.y * sv[d0 + 1] + w4.z * sv[d0 + 2] + w4.w * sv[d0 + 3];
    }
    acc += __shfl_xor(acc, 1);
    acc += __shfl_xor(acc, 2);
    acc += __shfl_xor(acc, 4);
    if (p == 0) m[b * CIN + i] = acc + ab[i] + 1.0f;
}

// ---------------------------------------------------------------------------
// K2: merged prep. Blocks [0,256): weight repack + dinv. Blocks [256,784):
// x modulate + NCHW fp32 -> zero-padded NHWC bf16 transpose.
__global__ void k_prep(const float* __restrict__ w, const float* __restrict__ m,
                       const float* __restrict__ x,
                       unsigned short* __restrict__ wb, float* __restrict__ dinv,
                       unsigned short* __restrict__ xp) {
    __shared__ float red[4][8];
    int tid = threadIdx.x;

    if (blockIdx.x < COUT) {
        // ---- weight repack + demod sum ----
        int o = blockIdx.x, i = tid;
        const float* wp = w + ((size_t)o * CIN + i) * 9;
        float v[9];
        float q = 0.f;
#pragma unroll
        for (int t = 0; t < 9; ++t) { v[t] = wp[t]; q += v[t] * v[t]; }
#pragma unroll
        for (int t = 0; t < 9; ++t)
            wb[((size_t)t * COUT + o) * CIN + i] = f2bf(v[t]);

        float r[8];
#pragma unroll
        for (int b = 0; b < 8; ++b) {
            float mv = m[b * CIN + i];
            r[b] = q * mv * mv;
        }
#pragma unroll
        for (int b = 0; b < 8; ++b) {
            r[b] += __shfl_xor(r[b], 1);
            r[b] += __shfl_xor(r[b], 2);
            r[b] += __shfl_xor(r[b], 4);
            r[b] += __shfl_xor(r[b], 8);
            r[b] += __shfl_xor(r[b], 16);
            r[b] += __shfl_xor(r[b], 32);
        }
        int lane = i & 63, wid = i >> 6;
        if (lane == 0) {
#pragma unroll
            for (int b = 0; b < 8; ++b) red[wid][b] = r[b];
        }
        __syncthreads();
        if (i < 8) {
            float acc = red[0][i] + red[1][i] + red[2][i] + red[3][i];
            dinv[i * COUT + o] = rsqrtf(acc + 1e-8f);
        }
        return;
    }

    // ---- x' = x * m, register transpose ----
    int bi = blockIdx.x - COUT;
    int b = bi / HP, yp = bi % HP;
    unsigned short* row = xp + ((size_t)(b * HP + yp)) * HP * CIN;

    if (yp == 0 || yp == HP - 1) {
        uint4 z = {0u, 0u, 0u, 0u};
        uint4* r = (uint4*)row;
        for (int j = tid; j < HP * CIN / 8; j += 256) r[j] = z;
        return;
    }
    int y = yp - 1;

    if (tid < 64) {
        uint4 z = {0u, 0u, 0u, 0u};
        if (tid < 32) ((uint4*)row)[tid] = z;
        else ((uint4*)(row + (size_t)(HP - 1) * CIN))[tid - 32] = z;
    }

#pragma unroll
    for (int it = 0; it < 2; ++it) {
        int u = it * 256 + tid;
        int x0 = (u & 15) * 4;
        int i0 = (u >> 4) * 8;
        float vv[8][4];
        float mv[8];
#pragma unroll
        for (int k = 0; k < 8; ++k) {
            *(float4*)vv[k] = *(const float4*)&x[(((size_t)b * CIN + i0 + k) * HH + y) * WW + x0];
            mv[k] = m[b * CIN + i0 + k];
        }
#pragma unroll
        for (int j = 0; j < 4; ++j) {
            short8 p;
#pragma unroll
            for (int k = 0; k < 8; ++k)
                p[k] = (short)f2bf(vv[k][j] * mv[k]);
            *(short8*)&row[(size_t)(x0 + j + 1) * CIN + i0] = p;
        }
    }
}

// ---------------------------------------------------------------------------
// K3: implicit GEMM conv, barrier-free steady state.
// Tile 128x128, 4 waves = 2m x 2n (64x64 each, full K per wave, no k-split).
// A: LDS, double-buffered across kc (k=64 chunks), staged via async16 with
//    XOR swizzle; ONE barrier per kc (5 total).
// B: straight from global (wb is channel-contiguous, L1/L2-resident);
//    register double-buffer one tap ahead hides L2 latency.
// Per tap per wave: 8 global dwordx4 (B) + 8 ds_read_b128 (A) + 32 MFMA.
__global__ void __launch_bounds__(256, 2)
k_conv(const unsigned short* __restrict__ xp,
       const unsigned short* __restrict__ wb,
       const float* __restrict__ dinv,
       const float* __restrict__ bias,
       float* __restrict__ out) {
    __shared__ unsigned short Ar[2 * 16896];   // 67584 B: 2 bufs x [4 rows][66 cols][8 x 16B]

    int bx = blockIdx.x;
    int mt = bx & 255;          // bx and bx+256 share the M-tile -> same XCD
    int n0 = (bx >> 8) << 7;
    int m0 = mt << 7;
    int b  = m0 >> 12;
    int y0 = (m0 >> 6) & 63;

    int tid = threadIdx.x;
    int lane = tid & 63, wid = tid >> 6;
    int mhalf = wid & 1, nhalf = wid >> 1;
    int wm = mhalf << 6, wn = nhalf << 6;
    int quad = lane >> 4, mrow = lane & 15;

    f32x4 acc[4][4] = {};

    const unsigned short* xb = xp + (size_t)b * HP * HP * CIN;

    auto stageA = [&](int kc, int bufOff) {
        int ch0 = kc * 64;
#pragma unroll
        for (int k = 0; k < 8; ++k) {
            int sA = k * 256 + tid;
            int rowA = sA / 528;
            int rem = sA - rowA * 528;
            int colA = rem >> 3, c4 = rem & 7;
            async16(xb + ((size_t)(y0 + rowA) * HP + colA) * CIN + ch0 + ((c4 ^ (colA & 7)) << 3),
                    &Ar[bufOff + sA * 8]);
        }
        if (tid < 64) {   // tail = exactly wave 0
            int sA = 2048 + tid;
            int rowA = sA / 528;
            int rem = sA - rowA * 528;
            int colA = rem >> 3, c4 = rem & 7;
            async16(xb + ((size_t)(y0 + rowA) * HP + colA) * CIN + ch0 + ((c4 ^ (colA & 7)) << 3),
                    &Ar[bufOff + sA * 8]);
        }
    };

    auto loadB = [&](short8 bf[2][4], int tt, int kcc) {
        const unsigned short* bp =
            wb + ((size_t)tt * COUT + n0 + wn + mrow) * CIN + kcc * 64 + quad * 8;
#pragma unroll
        for (int h = 0; h < 2; ++h)
#pragma unroll
            for (int j = 0; j < 4; ++j)
                bf[h][j] = *(const short8*)(bp + (size_t)j * 16 * CIN + h * 32);
    };

    short8 bcur[2][4], bnxt[2][4];
    stageA(0, 0);
    loadB(bcur, 0, 0);
    __syncthreads();
    int bufOff = 0;

#pragma unroll 1
    for (int kc = 0; kc < 4; ++kc) {
#pragma unroll
        for (int t = 0; t < 9; ++t) {
            // prefetch next tap's B (rolls across the kc boundary)
            if (t < 8) loadB(bnxt, t + 1, kc);
            else if (kc < 3) loadB(bnxt, 0, kc + 1);
            // A prefetch for next kc, issued after t=1's B so it doesn't gate it
            if (t == 0 && kc < 3) stageA(kc + 1, bufOff ^ 16896);

            int dy = t / 3, dx = t - dy * 3;
            int arow = mhalf + dy;
            short8 af[2][4];
#pragma unroll
            for (int h = 0; h < 2; ++h)
#pragma unroll
                for (int i = 0; i < 4; ++i) {
                    int xd = mrow + i * 16 + dx;
                    int chunk = arow * 528 + xd * 8 + ((h * 4 + quad) ^ (xd & 7));
                    af[h][i] = *(const short8*)&Ar[bufOff + chunk * 8];
                }
#pragma unroll
            for (int h = 0; h < 2; ++h)
#pragma unroll
                for (int i = 0; i < 4; ++i)
#pragma unroll
                    for (int j = 0; j < 4; ++j)
                        acc[i][j] = __builtin_amdgcn_mfma_f32_16x16x32_bf16(
                            af[h][i], bcur[h][j], acc[i][j], 0, 0, 0);
#pragma unroll
            for (int h = 0; h < 2; ++h)
#pragma unroll
                for (int j = 0; j < 4; ++j)
                    bcur[h][j] = bnxt[h][j];
        }
        __syncthreads();   // all waves done with bufOff; next-kc A stage drained
        bufOff ^= 16896;
    }

    // ---- Epilogue: *dinv + bias, f32x4 stores (4 consecutive x per lane-reg)
    // C/D layout: n(col) = mrow, m(row) = quad*4 + reg.
    int mbase = m0 + wm + quad * 4;
    int obase = n0 + wn + mrow;
#pragma unroll
    for (int j = 0; j < 4; ++j) {
        int o = obase + j * 16;
        float dv = dinv[b * COUT + o];
        float bv = bias[o];
#pragma unroll
        for (int i = 0; i < 4; ++i) {
            int mm = mbase + i * 16;
            int y = (mm >> 6) & 63, xx = mm & 63;
            f32x4 v = acc[i][j] * dv + bv;
            *(f32x4*)(out + (((size_t)(b * COUT + o) * HH + y) * WW + xx)) = v;
        }
    }
}

// ---------------------------------------------------------------------------
extern "C" void kernel_launch(void* const* d_in, const int* in_sizes, int n_in,
                              void* d_out, int out_size, void* d_ws, size_t ws_size,
                              hipStream_t stream) {
    const float* x    = (const float*)d_in[0];  // [8,256,64,64]
    const float* s    = (const float*)d_in[1];  // [8,512]
    const float* w    = (const float*)d_in[2];  // [256,256,3,3]
    const float* bias = (const float*)d_in[3];  // [256,1,1]
    const float* aw   = (const float*)d_in[4];  // [256,512]
    const float* ab   = (const float*)d_in[5];  // [256]
    float* out = (float*)d_out;

    char* ws = (char*)d_ws;
    float* m            = (float*)(ws + 0);                 //  8 KB [8][256]
    float* dinv         = (float*)(ws + 8192);              //  8 KB [8][256]
    unsigned short* wb  = (unsigned short*)(ws + 16384);    // 1.18 MB [9][256][256]
    unsigned short* xpb = (unsigned short*)(ws + 1196032);  // 17.8 MB [8][66][66][256]

    k_style<<<64, 256, 0, stream>>>(s, aw, ab, m);
    k_prep<<<COUT + BS * HP, 256, 0, stream>>>(w, m, x, wb, dinv, xpb);
    k_conv<<<512, 256, 0, stream>>>(xpb, wb, dinv, bias, out);
}

// Round 5
// 133.513 us; speedup vs baseline: 1.2793x; 1.2793x over previous
//
#include <hip/hip_runtime.h>
#include <hip/hip_bf16.h>
#include <stdint.h>

// Problem constants
#define BS   8
#define CIN  256
#define COUT 256
#define SD   512
#define HH   64
#define WW   64
#define HP   66   // padded spatial dim

typedef __attribute__((ext_vector_type(8))) short short8;
typedef __attribute__((ext_vector_type(4))) float f32x4;

__device__ __forceinline__ unsigned short f2bf(float f) {
    __hip_bfloat16 h = __float2bfloat16(f);
    return *reinterpret_cast<unsigned short*>(&h);
}

typedef __attribute__((address_space(3))) unsigned int lds_u32_t;
typedef const __attribute__((address_space(1))) unsigned int glb_u32_t;

__device__ __forceinline__ void async16(const void* g, void* l) {
    __builtin_amdgcn_global_load_lds((glb_u32_t*)g, (lds_u32_t*)l, 16, 0, 0);
}

// ---------------------------------------------------------------------------
// K1: m[b,i] = s[b,:].aw[i,:] + ab[i] + 1
__global__ void k_style(const float* __restrict__ s, const float* __restrict__ aw,
                        const float* __restrict__ ab, float* __restrict__ m) {
    int b = blockIdx.x >> 3, chunk = blockIdx.x & 7;
    int tid = threadIdx.x;
    __shared__ float sv[SD];
    for (int d = tid; d < SD; d += 256) sv[d] = s[b * SD + d];
    __syncthreads();
    int il = tid >> 3, p = tid & 7;
    int i = chunk * 32 + il;
    const float4* awr = (const float4*)(aw + (size_t)i * SD + p * 64);
    float acc = 0.f;
#pragma unroll
    for (int d4 = 0; d4 < 16; ++d4) {
        float4 w4 = awr[d4];
        int d0 = p * 64 + d4 * 4;
        acc += w4.x * sv[d0] + w4.y * sv[d0 + 1] + w4.z * sv[d0 + 2] + w4.w * sv[d0 + 3];
    }
    acc += __shfl_xor(acc, 1);
    acc += __shfl_xor(acc, 2);
    acc += __shfl_xor(acc, 4);
    if (p == 0) m[b * CIN + i] = acc + ab[i] + 1.0f;
}

// ---------------------------------------------------------------------------
// K2: merged prep. Blocks [0,256): weight repack + dinv. Blocks [256,784):
// x modulate + NCHW fp32 -> zero-padded NHWC bf16 transpose.
__global__ void k_prep(const float* __restrict__ w, const float* __restrict__ m,
                       const float* __restrict__ x,
                       unsigned short* __restrict__ wb, float* __restrict__ dinv,
                       unsigned short* __restrict__ xp) {
    __shared__ float red[4][8];
    int tid = threadIdx.x;

    if (blockIdx.x < COUT) {
        int o = blockIdx.x, i = tid;
        const float* wp = w + ((size_t)o * CIN + i) * 9;
        float v[9];
        float q = 0.f;
#pragma unroll
        for (int t = 0; t < 9; ++t) { v[t] = wp[t]; q += v[t] * v[t]; }
#pragma unroll
        for (int t = 0; t < 9; ++t)
            wb[((size_t)t * COUT + o) * CIN + i] = f2bf(v[t]);

        float r[8];
#pragma unroll
        for (int b = 0; b < 8; ++b) {
            float mv = m[b * CIN + i];
            r[b] = q * mv * mv;
        }
#pragma unroll
        for (int b = 0; b < 8; ++b) {
            r[b] += __shfl_xor(r[b], 1);
            r[b] += __shfl_xor(r[b], 2);
            r[b] += __shfl_xor(r[b], 4);
            r[b] += __shfl_xor(r[b], 8);
            r[b] += __shfl_xor(r[b], 16);
            r[b] += __shfl_xor(r[b], 32);
        }
        int lane = i & 63, wid = i >> 6;
        if (lane == 0) {
#pragma unroll
            for (int b = 0; b < 8; ++b) red[wid][b] = r[b];
        }
        __syncthreads();
        if (i < 8) {
            float acc = red[0][i] + red[1][i] + red[2][i] + red[3][i];
            dinv[i * COUT + o] = rsqrtf(acc + 1e-8f);
        }
        return;
    }

    int bi = blockIdx.x - COUT;
    int b = bi / HP, yp = bi % HP;
    unsigned short* row = xp + ((size_t)(b * HP + yp)) * HP * CIN;

    if (yp == 0 || yp == HP - 1) {
        uint4 z = {0u, 0u, 0u, 0u};
        uint4* r = (uint4*)row;
        for (int j = tid; j < HP * CIN / 8; j += 256) r[j] = z;
        return;
    }
    int y = yp - 1;

    if (tid < 64) {
        uint4 z = {0u, 0u, 0u, 0u};
        if (tid < 32) ((uint4*)row)[tid] = z;
        else ((uint4*)(row + (size_t)(HP - 1) * CIN))[tid - 32] = z;
    }

#pragma unroll
    for (int it = 0; it < 2; ++it) {
        int u = it * 256 + tid;
        int x0 = (u & 15) * 4;
        int i0 = (u >> 4) * 8;
        float vv[8][4];
        float mv[8];
#pragma unroll
        for (int k = 0; k < 8; ++k) {
            *(float4*)vv[k] = *(const float4*)&x[(((size_t)b * CIN + i0 + k) * HH + y) * WW + x0];
            mv[k] = m[b * CIN + i0 + k];
        }
#pragma unroll
        for (int j = 0; j < 4; ++j) {
            short8 p;
#pragma unroll
            for (int k = 0; k < 8; ++k)
                p[k] = (short)f2bf(vv[k][j] * mv[k]);
            *(short8*)&row[(size_t)(x0 + j + 1) * CIN + i0] = p;
        }
    }
}

// ---------------------------------------------------------------------------
// K3: implicit GEMM conv, 256m x 64n tile (vmem-byte minimized).
// Grid 512 = 128 M-tiles x 4 N-tiles; same-M tiles land on the same XCD
// (bx%8 == mt%8), so per-XCD A slice (~2.2MB) + B (1.2MB) stay L2-resident.
// 4 waves stacked in m: wave w = image row y0+w, 64 n cols, full K.
// A: single LDS buffer [6 rows][66 cols][64ch], restaged per kc (4x).
// B: TRIPLE-buffered 8KB taps, prefetch depth 2 (~2 taps of cover vs
//    ~300cy L2 latency), one barrier per tap.
// Staged bytes: A 203KB + B 288KB = 491KB/block (round3: 711KB).
__global__ void __launch_bounds__(256, 2)
k_conv(const unsigned short* __restrict__ xp,
       const unsigned short* __restrict__ wb,
       const float* __restrict__ dinv,
       const float* __restrict__ bias,
       float* __restrict__ out) {
    __shared__ unsigned short Ar[3168 * 8];      // 50688 B: [6 rows][66 cols][8 x 16B]
    __shared__ unsigned short Bs[3 * 512 * 8];   // 24576 B: 3 bufs x [64 rows][8 x 16B]

    int bx = blockIdx.x;
    int mt = bx & 127;
    int n0 = (bx >> 7) << 6;      // 4 N-tiles of 64
    int m0 = mt << 8;             // 256 m per tile
    int b  = m0 >> 12;
    int y0 = (m0 >> 6) & 63;      // image row base (tile = rows y0..y0+3)

    int tid = threadIdx.x;
    int lane = tid & 63, w = tid >> 6;
    int quad = lane >> 4, mrow = lane & 15;

    f32x4 acc[4][4] = {};

    const unsigned short* xb = xp + (size_t)b * HP * HP * CIN;

    auto stageA = [&](int kc) {
        int ch0 = kc * 64;
#pragma unroll
        for (int k = 0; k < 12; ++k) {
            int sA = k * 256 + tid;
            int rowA = sA / 528;
            int rem = sA - rowA * 528;
            int colA = rem >> 3, c4 = rem & 7;
            async16(xb + ((size_t)(y0 + rowA) * HP + colA) * CIN + ch0 + ((c4 ^ (colA & 7)) << 3),
                    &Ar[sA * 8]);
        }
        if (tid < 96) {   // tail: 3168 - 3072
            int sA = 3072 + tid;
            int rowA = sA / 528;
            int rem = sA - rowA * 528;
            int colA = rem >> 3, c4 = rem & 7;
            async16(xb + ((size_t)(y0 + rowA) * HP + colA) * CIN + ch0 + ((c4 ^ (colA & 7)) << 3),
                    &Ar[sA * 8]);
        }
    };

    auto stageB = [&](int tt, int kcc, int buf) {
        const unsigned short* bp = wb + ((size_t)tt * COUT + n0) * CIN + kcc * 64;
        unsigned short* dst = Bs + buf * 4096;
#pragma unroll
        for (int k = 0; k < 2; ++k) {
            int sB = k * 256 + tid;
            int rowB = sB >> 3, c4 = sB & 7;
            async16(bp + (size_t)rowB * CIN + ((c4 ^ (rowB & 7)) << 3), dst + sB * 8);
        }
    };

    stageA(0);
    stageB(0, 0, 0);
    stageB(1, 0, 1);
    __syncthreads();

#pragma unroll 1
    for (int kc = 0; kc < 4; ++kc) {
#pragma unroll
        for (int t = 0; t < 9; ++t) {
            // prefetch B two taps ahead (buf index (g+2)%3 folds at compile time)
            if (t < 7) stageB(t + 2, kc, (t + 2) % 3);
            else if (kc < 3) stageB(t - 7, kc + 1, (t + 2) % 3);

            int dy = t / 3, dx = t - dy * 3;
            int arow = w + dy;
            const unsigned short* Bcur = Bs + (t % 3) * 4096;

            short8 af[2][4], bf[2][4];
#pragma unroll
            for (int h = 0; h < 2; ++h)
#pragma unroll
                for (int i = 0; i < 4; ++i) {
                    int col = mrow + i * 16 + dx;
                    int chunk = arow * 528 + col * 8 + ((h * 4 + quad) ^ (col & 7));
                    af[h][i] = *(const short8*)&Ar[chunk * 8];
                }
#pragma unroll
            for (int h = 0; h < 2; ++h)
#pragma unroll
                for (int j = 0; j < 4; ++j) {
                    int rowB = mrow + j * 16;
                    int chunk = rowB * 8 + ((h * 4 + quad) ^ (rowB & 7));
                    bf[h][j] = *(const short8*)&Bcur[chunk * 8];
                }
#pragma unroll
            for (int h = 0; h < 2; ++h)
#pragma unroll
                for (int i = 0; i < 4; ++i)
#pragma unroll
                    for (int j = 0; j < 4; ++j)
                        acc[i][j] = __builtin_amdgcn_mfma_f32_16x16x32_bf16(
                            af[h][i], bf[h][j], acc[i][j], 0, 0, 0);

            __syncthreads();
            if (t == 8 && kc < 3) {   // A single-buffer restage (exposed, 3x)
                stageA(kc + 1);
                __syncthreads();
            }
        }
    }

    // ---- Epilogue: *dinv + bias. Wave w owns image row y0+w.
    // C/D layout: n(col) = mrow, x = quad*4 + reg + i*16.
    int y = y0 + w;
#pragma unroll
    for (int j = 0; j < 4; ++j) {
        int o = n0 + mrow + j * 16;
        float dv = dinv[b * COUT + o];
        float bv = bias[o];
#pragma unroll
        for (int i = 0; i < 4; ++i) {
            int xx = i * 16 + quad * 4;
            f32x4 v = acc[i][j] * dv + bv;
            *(f32x4*)(out + (((size_t)(b * COUT + o) * HH + y) * WW + xx)) = v;
        }
    }
}

// ---------------------------------------------------------------------------
extern "C" void kernel_launch(void* const* d_in, const int* in_sizes, int n_in,
                              void* d_out, int out_size, void* d_ws, size_t ws_size,
                              hipStream_t stream) {
    const float* x    = (const float*)d_in[0];  // [8,256,64,64]
    const float* s    = (const float*)d_in[1];  // [8,512]
    const float* w    = (const float*)d_in[2];  // [256,256,3,3]
    const float* bias = (const float*)d_in[3];  // [256,1,1]
    const float* aw   = (const float*)d_in[4];  // [256,512]
    const float* ab   = (const float*)d_in[5];  // [256]
    float* out = (float*)d_out;

    char* ws = (char*)d_ws;
    float* m            = (float*)(ws + 0);                 //  8 KB [8][256]
    float* dinv         = (float*)(ws + 8192);              //  8 KB [8][256]
    unsigned short* wb  = (unsigned short*)(ws + 16384);    // 1.18 MB [9][256][256]
    unsigned short* xpb = (unsigned short*)(ws + 1196032);  // 17.8 MB [8][66][66][256]

    k_style<<<64, 256, 0, stream>>>(s, aw, ab, m);
    k_prep<<<COUT + BS * HP, 256, 0, stream>>>(w, m, x, wb, dinv, xpb);
    k_conv<<<512, 256, 0, stream>>>(xpb, wb, dinv, bias, out);
}